// Round 2
// baseline (307.080 us; speedup 1.0000x reference)
//
#include <hip/hip_runtime.h>
#include <math.h>

namespace {
constexpr int NB = 4, NCHT = 29, NF = 19, NM = 7, NHI = 3;
constexpr int HH = 512, WW = 512;
constexpr int PH  = 170;           // pooled H/W (512-3)/3+1
constexpr int NHW = 168;           // shifted-view grid 170-3+1
constexpr int NS  = NHW * NHW;     // 28224 samples
constexpr int NWG = 171;           // window grid incl. 2-pixel edge strips
constexpr int NBC = NB * NCHT;     // 116 (b,c) pairs
constexpr int NCHUNK = 16;
constexpr int CHS = NS / NCHUNK;   // 1764

constexpr int F2M[NF] = {0,0,0,1,1,1,2,2,3,3,4,5,5,6,6,6,6,6,6};
constexpr int M2H[NM] = {0,0,1,1,1,2,2};
constexpr int F2H[NF] = {0,0,0,0,0,0,1,1,1,1,1,2,2,2,2,2,2,2,2};

constexpr unsigned long long packTbl(const int* a, int n) {
  unsigned long long p = 0;
  for (int i = 0; i < n; i++) p |= (unsigned long long)(a[i]) << (3 * i);
  return p;
}
constexpr unsigned long long PF2M = packTbl(F2M, NF);
constexpr unsigned long long PF2H = packTbl(F2H, NF);

// ws float layout
constexpr int    WS_ACC = 0;     // [0]=bceF [1]=bceM [2]=bceH [3]=cnt [4]=rmi
constexpr int    WS_S1  = 16;    // 116*32
constexpr int    WS_COV = 4096;  // 116*324
constexpr size_t WS_LA  = 65536;
constexpr size_t WS_PR  = WS_LA + (size_t)NBC * PH * PH;
constexpr size_t WS_ZERO_BYTES = (size_t)(WS_COV + NBC * 324) * 4;
} // namespace

// ---------------- kernel A: sigmoid + hierarchy + BCE + 3x3 maxpool ----------
__global__ __launch_bounds__(256)
void kA(const float* __restrict__ cls, const int* __restrict__ label,
        float* __restrict__ ws) {
  const int flat = blockIdx.x * blockDim.x + threadIdx.x;
  const int total = NB * NWG * NWG;
  float bce0 = 0.f, bce1 = 0.f, bce2 = 0.f, cnt = 0.f;
  if (flat < total) {
    const int wx = flat % NWG;
    const int wy = (flat / NWG) % NWG;
    const int b  = flat / (NWG * NWG);
    const bool interior = (wy < PH) && (wx < PH);
    const int ny = (wy == PH) ? 2 : 3;
    const int nx = (wx == PH) ? 2 : 3;

    float poolPr[NCHT];
    #pragma unroll
    for (int c = 0; c < NCHT; c++) poolPr[c] = 0.f;
    int maskF = 0, maskM = 0, maskH = 0;

    for (int dy = 0; dy < ny; dy++)
      for (int dx = 0; dx < nx; dx++) {
        const int y = 3 * wy + dy, x = 3 * wx + dx;
        const int lbl = label[((size_t)b * HH + y) * WW + x];
        const bool valid = (lbl != 255);
        const int lf = valid ? lbl : 0;
        const int lm = (int)((PF2M >> (3 * lf)) & 7ull);
        const int lh = (int)((PF2H >> (3 * lf)) & 7ull);
        const float vm = valid ? 1.f : 0.f;

        const float* cp = cls + ((size_t)(b * NCHT) * HH + y) * WW + x;
        float p[NCHT];
        #pragma unroll
        for (int c = 0; c < NCHT; c++)
          p[c] = 1.f / (1.f + __expf(-cp[(size_t)c * HH * WW]));

        float segf[NM];
        #pragma unroll
        for (int m = 0; m < NM; m++) segf[m] = -1.f;
        #pragma unroll
        for (int f = 0; f < NF; f++) segf[F2M[f]] = fmaxf(segf[F2M[f]], p[f]);
        float pBc[NM];
        #pragma unroll
        for (int m = 0; m < NM; m++) pBc[m] = fmaxf(segf[m], p[NF + m]);
        float segm[NHI];
        #pragma unroll
        for (int k = 0; k < NHI; k++) segm[k] = -1.f;
        #pragma unroll
        for (int m = 0; m < NM; m++) segm[M2H[m]] = fmaxf(segm[M2H[m]], pBc[m]);
        float pCc[NHI];
        #pragma unroll
        for (int k = 0; k < NHI; k++) pCc[k] = fmaxf(segm[k], p[NF + NM + k]);

        // fine: pos = min(pA, pB[f2m]), neg = pA
        #pragma unroll
        for (int f = 0; f < NF; f++) {
          const float pos = fminf(p[f], p[NF + F2M[f]]);
          if (valid)
            bce0 += (f == lf) ? -__logf(pos + 1e-8f) : -__logf(1.f - p[f] + 1e-8f);
          if (interior) poolPr[f] = fmaxf(poolPr[f], pos * vm + 1e-6f);
        }
        // mid: pos = min(pB, pC[m2h]), neg = pBc
        #pragma unroll
        for (int m = 0; m < NM; m++) {
          const float pos = fminf(p[NF + m], p[NF + NM + M2H[m]]);
          if (valid)
            bce1 += (m == lm) ? -__logf(pos + 1e-8f) : -__logf(1.f - pBc[m] + 1e-8f);
          if (interior) poolPr[NF + m] = fmaxf(poolPr[NF + m], pos * vm + 1e-6f);
        }
        // high: pos = pC, neg = pCc
        #pragma unroll
        for (int k = 0; k < NHI; k++) {
          const float pos = p[NF + NM + k];
          if (valid)
            bce2 += (k == lh) ? -__logf(pos + 1e-8f) : -__logf(1.f - pCc[k] + 1e-8f);
          if (interior) poolPr[NF + NM + k] = fmaxf(poolPr[NF + NM + k], pos * vm + 1e-6f);
        }
        if (interior && valid) {
          maskF |= 1 << lf; maskM |= 1 << lm; maskH |= 1 << lh;
        }
        cnt += vm;
      }

    if (interior) {
      float* la = ws + WS_LA;
      float* pr = ws + WS_PR;
      const size_t base = ((size_t)(b * NCHT) * PH + wy) * PH + wx;
      #pragma unroll
      for (int c = 0; c < NF; c++)
        la[base + (size_t)c * PH * PH] = (float)((maskF >> c) & 1);
      #pragma unroll
      for (int m = 0; m < NM; m++)
        la[base + (size_t)(NF + m) * PH * PH] = (float)((maskM >> m) & 1);
      #pragma unroll
      for (int k = 0; k < NHI; k++)
        la[base + (size_t)(NF + NM + k) * PH * PH] = (float)((maskH >> k) & 1);
      #pragma unroll
      for (int c = 0; c < NCHT; c++)
        pr[base + (size_t)c * PH * PH] = poolPr[c];
    }
  }
  // wave reduce + atomics
  #pragma unroll
  for (int m = 32; m >= 1; m >>= 1) {
    bce0 += __shfl_xor(bce0, m);
    bce1 += __shfl_xor(bce1, m);
    bce2 += __shfl_xor(bce2, m);
    cnt  += __shfl_xor(cnt, m);
  }
  if ((threadIdx.x & 63) == 0) {
    atomicAdd(&ws[0], bce0);
    atomicAdd(&ws[1], bce1);
    atomicAdd(&ws[2], bce2);
    atomicAdd(&ws[3], cnt);
  }
}

// ---------------- kernel S1: per-(b,c) row sums of the 18 shifted views ------
__global__ __launch_bounds__(256)
void kS1(const float* __restrict__ ws_base, float* __restrict__ s1out) {
  const int bc = blockIdx.x;
  const float* A = ws_base + WS_LA + (size_t)bc * PH * PH;
  const float* P = ws_base + WS_PR + (size_t)bc * PH * PH;
  float sums[18];
  #pragma unroll
  for (int r = 0; r < 18; r++) sums[r] = 0.f;
  for (int s = threadIdx.x; s < NS; s += blockDim.x) {
    const int sy = s / NHW, sx = s - sy * NHW;
    const int idx = sy * PH + sx;
    #pragma unroll
    for (int r = 0; r < 9; r++) sums[r] += A[idx + (r / 3) * PH + (r % 3)];
    #pragma unroll
    for (int r = 0; r < 9; r++) sums[9 + r] += P[idx + (r / 3) * PH + (r % 3)];
  }
  #pragma unroll
  for (int r = 0; r < 18; r++) {
    float v = sums[r];
    #pragma unroll
    for (int m = 32; m >= 1; m >>= 1) v += __shfl_xor(v, m);
    sums[r] = v;
  }
  __shared__ float lds[4][18];
  const int wave = threadIdx.x >> 6, lane = threadIdx.x & 63;
  if (lane == 0) {
    #pragma unroll
    for (int r = 0; r < 18; r++) lds[wave][r] = sums[r];
  }
  __syncthreads();
  if (threadIdx.x < 18)
    s1out[bc * 32 + threadIdx.x] =
        lds[0][threadIdx.x] + lds[1][threadIdx.x] + lds[2][threadIdx.x] + lds[3][threadIdx.x];
}

// ---------------- kernel Cov: CENTERED 18x18 second moments, 6x6 reg tiles --
__global__ __launch_bounds__(192)
void kCov(const float* __restrict__ ws_base, const float* __restrict__ s1,
          float* __restrict__ cov) {
  const int bc    = blockIdx.x / NCHUNK;
  const int chunk = blockIdx.x % NCHUNK;
  const int tile  = threadIdx.x / 32;
  const int g     = threadIdx.x % 32;
  // tiles: 0:(0,0) 1:(0,1) 2:(0,2) 3:(1,1) 4:(1,2) 5:(2,2)
  const int ta = (tile < 3) ? 0 : ((tile < 5) ? 1 : 2);
  const int tb = (tile < 3) ? tile : ((tile < 5) ? tile - 2 : 2);  // FIXED (was tile-1)
  const float* Abase = ws_base + WS_LA + (size_t)bc * PH * PH;
  const float* Pbase = ws_base + WS_PR + (size_t)bc * PH * PH;
  const float inv_n = 1.0f / (float)NS;

  const float* pA[6];
  const float* pB[6];
  float muA[6], muB[6];
  #pragma unroll
  for (int k = 0; k < 6; k++) {
    int r = 6 * ta + k; int rr = (r < 9) ? r : r - 9;
    pA[k]  = ((r < 9) ? Abase : Pbase) + (rr / 3) * PH + (rr % 3);
    muA[k] = s1[bc * 32 + r] * inv_n;
    int r2 = 6 * tb + k; int rr2 = (r2 < 9) ? r2 : r2 - 9;
    pB[k]  = ((r2 < 9) ? Abase : Pbase) + (rr2 / 3) * PH + (rr2 % 3);
    muB[k] = s1[bc * 32 + r2] * inv_n;
  }

  float acc[6][6];
  #pragma unroll
  for (int k = 0; k < 6; k++)
    #pragma unroll
    for (int l = 0; l < 6; l++) acc[k][l] = 0.f;

  int s = chunk * CHS + g;
  const int send = chunk * CHS + CHS;
  int sy = s / NHW, sx = s - sy * NHW;
  for (; s < send; s += 32) {
    const int idx = sy * PH + sx;
    float va[6], vb[6];
    #pragma unroll
    for (int k = 0; k < 6; k++) { va[k] = pA[k][idx] - muA[k]; vb[k] = pB[k][idx] - muB[k]; }
    #pragma unroll
    for (int k = 0; k < 6; k++)
      #pragma unroll
      for (int l = 0; l < 6; l++) acc[k][l] = fmaf(va[k], vb[l], acc[k][l]);
    sx += 32; if (sx >= NHW) { sx -= NHW; sy++; }
  }

  #pragma unroll
  for (int k = 0; k < 6; k++)
    #pragma unroll
    for (int l = 0; l < 6; l++) {
      float v = acc[k][l];
      #pragma unroll
      for (int m = 16; m >= 1; m >>= 1) v += __shfl_xor(v, m);
      acc[k][l] = v;
    }
  if (g == 0) {
    float* dst = cov + (size_t)bc * 324;
    #pragma unroll
    for (int k = 0; k < 6; k++)
      #pragma unroll
      for (int l = 0; l < 6; l++)
        atomicAdd(&dst[(6 * ta + k) * 18 + 6 * tb + l], acc[k][l]);
  }
}

// ---------------- kernel Solve: per-(b,c) 9x9 algebra in double --------------
__global__ void kSolve(const float* __restrict__ cov_all, float* __restrict__ acc) {
  const int bc = blockIdx.x * blockDim.x + threadIdx.x;
  if (bc >= NBC) return;
  const float* cr = cov_all + (size_t)bc * 324;
  double C[18][18];
  for (int i = 0; i < 18; i++)
    for (int j = i; j < 18; j++)
      C[i][j] = (double)cr[i * 18 + j];

  // Cholesky of pr_cov + 1e-3 I  (P(i,j) j<=i -> upper C[9+j][9+i])
  double L[9][9];
  for (int i = 0; i < 9; i++)
    for (int j = 0; j <= i; j++) {
      double s = C[9 + j][9 + i];
      if (i == j) s += 1e-3;
      for (int k = 0; k < j; k++) s -= L[i][k] * L[j][k];
      L[i][j] = (i == j) ? sqrt(fmax(s, 1e-300)) : s / L[j][j];
    }
  // M = L^{-1} * la_pr^T   (T[r][c] = la_pr[c][r] = C[c][9+r])
  double M[9][9];
  for (int c = 0; c < 9; c++)
    for (int r = 0; r < 9; r++) {
      double s = C[c][9 + r];
      for (int k = 0; k < r; k++) s -= L[r][k] * M[k][c];
      M[r][c] = s / L[r][r];
    }
  // appro = la_cov - M^T M + 1e-3 I, Cholesky, logdet
  double A2[9][9], L2[9][9];
  for (int i = 0; i < 9; i++)
    for (int j = 0; j <= i; j++) {
      double s = C[j][i];
      for (int r = 0; r < 9; r++) s -= M[r][i] * M[r][j];
      if (i == j) s += 1e-3;
      A2[i][j] = s;
    }
  double logdet = 0.0;
  for (int i = 0; i < 9; i++)
    for (int j = 0; j <= i; j++) {
      double s = A2[i][j];
      for (int k = 0; k < j; k++) s -= L2[i][k] * L2[j][k];
      if (i == j) {
        double d = sqrt(fmax(s, 0.0));
        L2[i][j] = d;
        logdet += 2.0 * log(d + 1e-8);
      } else L2[i][j] = s / L2[j][j];
    }
  atomicAdd(&acc[4], (float)logdet);
}

// ---------------- finalize ----------------------------------------------------
__global__ void kFin(const float* __restrict__ ws, float* __restrict__ out) {
  if (threadIdx.x == 0 && blockIdx.x == 0) {
    const double cnt = (double)ws[3];
    const double bce = 0.5 * ((double)ws[0] / (cnt * NF + 1e-8) +
                              (double)ws[1] / (cnt * NM + 1e-8) +
                              (double)ws[2] / (cnt * NHI + 1e-8));
    const double rmi = 0.5 * (double)ws[4] / (double)(NB * 9);
    out[0] = (float)(bce + rmi);
  }
}

extern "C" void kernel_launch(void* const* d_in, const int* in_sizes, int n_in,
                              void* d_out, int out_size, void* d_ws, size_t ws_size,
                              hipStream_t stream) {
  (void)in_sizes; (void)n_in; (void)out_size; (void)ws_size;
  const float* cls   = (const float*)d_in[3];
  const int*   label = (const int*)d_in[4];
  float* ws = (float*)d_ws;

  hipMemsetAsync(d_ws, 0, WS_ZERO_BYTES, stream);

  const int totalA = NB * NWG * NWG;
  kA<<<(totalA + 255) / 256, 256, 0, stream>>>(cls, label, ws);
  kS1<<<NBC, 256, 0, stream>>>(ws, ws + WS_S1);
  kCov<<<NBC * NCHUNK, 192, 0, stream>>>(ws, ws + WS_S1, ws + WS_COV);
  kSolve<<<(NBC + 63) / 64, 64, 0, stream>>>(ws + WS_COV, ws);
  kFin<<<1, 64, 0, stream>>>(ws, (float*)d_out);
}